// Round 9
// baseline (38.182 us; speedup 1.0000x reference)
//
#include <hip/hip_runtime.h>

#define NN 16384
#define NT 1024

// backward gather for slot K (compile-time constant usage contexts)
#define BWD_GATHER(K)                                                        \
    {                                                                        \
        unsigned int p2 = (pend >> (2 * (K))) & 3u;                          \
        int ns = sreg[(K)];                                                  \
        if (p2 & 1u) {                                                       \
            int c0 = (int)(short)(cpair[(K)] & 0xFFFFu);                     \
            int s = state[c0];                                               \
            ns |= s & 3;                                                     \
            if (s & 4) p2 &= ~1u;                                            \
        }                                                                    \
        if (p2 & 2u) {                                                       \
            int c1 = (int)(short)(cpair[(K)] >> 16);                         \
            int s = state[c1];                                               \
            ns |= s & 3;                                                     \
            if (s & 4) p2 &= ~2u;                                            \
        }                                                                    \
        if (p2 == 0u || (ns & 3) == 3) { ns |= 4; todo &= ~(1u << (K)); }    \
        pend = (pend & ~(3u << (2 * (K)))) | (p2 << (2 * (K)));              \
        if (ns != sreg[(K)]) {                                               \
            sreg[(K)] = ns;                                                  \
            state[((K) << 10) + tid] = (unsigned char)ns;                    \
            ch = true;                                                       \
        }                                                                    \
    }

__global__ __launch_bounds__(NT) void dag_eval_kernel(
    const int* __restrict__ left,
    const int* __restrict__ right,
    const unsigned char* __restrict__ reroll_raw,
    int* __restrict__ out)
{
    __shared__ __align__(16) unsigned int  pairs[NN];   // l16|r16<<16, 64 KB
    __shared__ __align__(16) unsigned char reach[NN];   // 0/1 bytes
    __shared__ __align__(16) unsigned char state[NN];   // hs|hr<<1|fin<<2
    __shared__ int flags[4];
    __shared__ int nzmask;
    __shared__ int cnt;

    const int tid = threadIdx.x;

    if (tid < 4)  flags[tid] = 0;
    if (tid == 0) { nzmask = 0; cnt = 0; }

    // ---- strided children: thread owns nodes (k<<10)+tid ----
    unsigned int cpair[16];
    #pragma unroll
    for (int k = 0; k < 16; ++k) {
        int l = left[(k << 10) + tid];
        int r = right[(k << 10) + tid];
        cpair[k] = (l & 0xFFFFu) | ((unsigned)r << 16);
        pairs[(k << 10) + tid] = cpair[k];
    }

    // ---- leaf_is_reroll layout probe (first 16 KB safe for all layouts) ----
    {
        uint4 v = ((const uint4*)reroll_raw)[tid];
        unsigned int t = v.x | v.y | v.z | v.w;
        unsigned int m = 0;
        if (t & 0x000000FFu) m |= 1u;
        if (t & 0x0000FF00u) m |= 2u;
        if (t & 0x00FF0000u) m |= 4u;
        if (t & 0xFF000000u) m |= 8u;
        if (m) atomicOr(&nzmask, (int)m);
    }
    *(uint4*)&reach[tid * 16] = make_uint4(0u, 0u, 0u, 0u);
    __syncthreads();

    const int mask   = nzmask;
    const int layout = ((mask & ~1) == 0) ? 0 : (((mask & 3) == 0) ? 1 : 2);
    const int*   ri = (const int*)reroll_raw;
    const float* rf = (const float*)reroll_raw;

    // ---- backward init: leaf bits + pending-internal-children mask ----
    int sreg[16];
    unsigned int todo = 0, pend = 0;
    #pragma unroll
    for (int k = 0; k < 16; ++k) {
        int c0 = (int)(short)(cpair[k] & 0xFFFFu);
        int c1 = (int)(short)(cpair[k] >> 16);
        int s = 0;
        unsigned int p2 = 0;
        if (c0 < 0) {
            int id = -c0 - 1;
            bool rr = (layout == 2) ? (reroll_raw[id] != 0)
                     : (layout == 1) ? (rf[id] != 0.0f)
                                     : (ri[id] != 0);
            s |= rr ? 2 : 1;
        } else p2 |= 1u;
        if (c1 < 0) {
            int id = -c1 - 1;
            bool rr = (layout == 2) ? (reroll_raw[id] != 0)
                     : (layout == 1) ? (rf[id] != 0.0f)
                                     : (ri[id] != 0);
            s |= rr ? 2 : 1;
        } else p2 |= 2u;
        if (p2 == 0u || s == 3) s |= 4;
        else { todo |= 1u << k; pend |= p2 << (2 * k); }
        sreg[k] = s;
        state[(k << 10) + tid] = (unsigned char)s;
    }
    if (tid == 0) reach[0] = 1;
    __syncthreads();

    // ---- fixed schedule: 16 fused phases (fwd chunk c asc, bwd chunk 15-c desc) ----
    unsigned int pushedC = 0;
    #pragma unroll
    for (int c = 0; c < 16; ++c) {
        // forward chunk c: one node per thread
        {
            if (reach[(c << 10) + tid]) {
                pushedC |= 1u << c;
                int c0 = (int)(short)(cpair[c] & 0xFFFFu);
                int c1 = (int)(short)(cpair[c] >> 16);
                if (c0 > 0) reach[c0] = (unsigned char)1;
                if (c1 > 0) reach[c1] = (unsigned char)1;
            }
        }
        // backward chunk 15-c: two gather attempts (2nd resolves same-wave chains)
        {
            bool ch = false;  // consumed only by macro; phase has no flags
            if ((todo >> (15 - c)) & 1u) BWD_GATHER(15 - c);
            if ((todo >> (15 - c)) & 1u) BWD_GATHER(15 - c);
            (void)ch;
        }
        __syncthreads();
    }

    // ---- exact cleanup fixpoint (flags-checked), expected ~2-4 sweeps ----
    for (int w = 0; w < 600; ++w) {
        bool ch = false;

        // forward: poll unpushed slots, push-once
        unsigned int np = 0;
        #pragma unroll
        for (int k = 0; k < 16; ++k)
            if (!((pushedC >> k) & 1u) && reach[(k << 10) + tid]) np |= 1u << k;
        if (np) {
            pushedC |= np;
            ch = true;
            #pragma unroll
            for (int k = 0; k < 16; ++k) {
                if ((np >> k) & 1u) {
                    int c0 = (int)(short)(cpair[k] & 0xFFFFu);
                    int c1 = (int)(short)(cpair[k] >> 16);
                    if (c0 > 0) reach[c0] = (unsigned char)1;
                    if (c1 > 0) reach[c1] = (unsigned char)1;
                }
            }
        }

        // backward: todo-masked gathers
        if (todo) {
            #pragma unroll
            for (int k = 0; k < 16; ++k)
                if ((todo >> k) & 1u) BWD_GATHER(k);
        }

        if (ch) flags[w & 3] = 1;
        __syncthreads();
        int f = flags[w & 3];
        if (tid == 0) flags[(w + 2) & 3] = 0;
        if (!f) break;
    }

    // ---- count: linear reach read, byte-sum, one atomic per wave ----
    uint4 v = *(const uint4*)&reach[tid * 16];
    {
        unsigned int t = v.x + v.y + v.z + v.w;
        int cc = (t & 0xFF) + ((t >> 8) & 0xFF) + ((t >> 16) & 0xFF) + (t >> 24);
        #pragma unroll
        for (int off = 32; off; off >>= 1) cc += __shfl_down(cc, off);
        if ((tid & 63) == 0) atomicAdd(&cnt, cc);
    }

    // ---- outputs: linear LDS reads, int4 stores ----
    int4* out4 = (int4*)out;
    {
        unsigned int wd[4] = {v.x, v.y, v.z, v.w};
        #pragma unroll
        for (int j = 0; j < 4; ++j) {
            int4 a;
            a.x = (wd[j] >> 0)  & 1;
            a.y = (wd[j] >> 8)  & 1;
            a.z = (wd[j] >> 16) & 1;
            a.w = (wd[j] >> 24) & 1;
            out4[(tid * 16 >> 2) + j] = a;
        }
    }
    {
        uint4 sv = *(const uint4*)&state[tid * 16];
        unsigned int wd[4] = {sv.x, sv.y, sv.z, sv.w};
        #pragma unroll
        for (int j = 0; j < 4; ++j) {
            int4 h, r;
            h.x = (wd[j] >> 0)  & 1; h.y = (wd[j] >> 8)  & 1;
            h.z = (wd[j] >> 16) & 1; h.w = (wd[j] >> 24) & 1;
            r.x = (wd[j] >> 1)  & 1; r.y = (wd[j] >> 9)  & 1;
            r.z = (wd[j] >> 17) & 1; r.w = (wd[j] >> 25) & 1;
            out4[((NN + tid * 16) >> 2) + j]     = h;
            out4[((2 * NN + tid * 16) >> 2) + j] = r;
        }
    }
    __syncthreads();
    if (tid == 0) out[3 * NN] = cnt;
}

extern "C" void kernel_launch(void* const* d_in, const int* in_sizes, int n_in,
                              void* d_out, int out_size, void* d_ws, size_t ws_size,
                              hipStream_t stream)
{
    const int* left  = (const int*)d_in[3];
    const int* right = (const int*)d_in[4];
    const unsigned char* reroll = (const unsigned char*)d_in[5];
    int* out = (int*)d_out;
    dag_eval_kernel<<<1, NT, 0, stream>>>(left, right, reroll, out);
}

// Round 10
// 35.462 us; speedup vs baseline: 1.0767x; 1.0767x over previous
//
#include <hip/hip_runtime.h>

#define NN 16384
#define NT 1024
#define PER 16
#define SW1 8

__global__ __launch_bounds__(NT) void dag_eval_kernel(
    const int* __restrict__ left,
    const int* __restrict__ right,
    const unsigned char* __restrict__ reroll_raw,
    int* __restrict__ out)
{
    __shared__ __align__(16) unsigned int  pairs[NN];       // l16|r16<<16, 64 KB
    __shared__ __align__(16) unsigned char reach[NN];       // phase-1 bytes
    __shared__ __align__(16) unsigned char state[NN + 16];  // hs|hr<<1|fin<<2; dummy=4
    __shared__ __align__(16) unsigned int  bits[NN / 32];   // phase-2 fwd bitset
    __shared__ unsigned short wl[NN];                       // backward worklist
    __shared__ int wl_n;
    __shared__ int nzmask;
    __shared__ int cnt;

    const int tid = threadIdx.x;
    const int b0  = tid * PER;

    if (tid == 0) { nzmask = 0; cnt = 0; wl_n = 0; }
    if (tid < 16) state[NN + tid] = 4;

    // ---- children -> registers + LDS pairs table (coalesced int4) ----
    unsigned int cpair[PER];
    {
        const int4* l4 = (const int4*)left;
        const int4* r4 = (const int4*)right;
        #pragma unroll
        for (int j = 0; j < PER / 4; ++j) {
            int4 a = l4[(b0 >> 2) + j];
            int4 b = r4[(b0 >> 2) + j];
            cpair[4*j+0] = (a.x & 0xFFFFu) | ((unsigned)b.x << 16);
            cpair[4*j+1] = (a.y & 0xFFFFu) | ((unsigned)b.y << 16);
            cpair[4*j+2] = (a.z & 0xFFFFu) | ((unsigned)b.z << 16);
            cpair[4*j+3] = (a.w & 0xFFFFu) | ((unsigned)b.w << 16);
            *(uint4*)&pairs[b0 + 4*j] = make_uint4(cpair[4*j+0], cpair[4*j+1],
                                                   cpair[4*j+2], cpair[4*j+3]);
        }
    }

    // ---- leaf_is_reroll layout probe (first 16 KB safe for all layouts) ----
    {
        uint4 v = ((const uint4*)reroll_raw)[tid];
        unsigned int t = v.x | v.y | v.z | v.w;
        unsigned int m = 0;
        if (t & 0x000000FFu) m |= 1u;
        if (t & 0x0000FF00u) m |= 2u;
        if (t & 0x00FF0000u) m |= 4u;
        if (t & 0xFF000000u) m |= 8u;
        if (m) atomicOr(&nzmask, (int)m);
    }
    *(uint4*)&reach[b0] = make_uint4(0u, 0u, 0u, 0u);
    __syncthreads();

    const int mask   = nzmask;
    const int layout = ((mask & ~1) == 0) ? 0 : (((mask & 3) == 0) ? 1 : 2);
    const int*   ri = (const int*)reroll_raw;
    const float* rf = (const float*)reroll_raw;

    // ---- backward init: leaf bits; final if both children leaves or saturated ----
    int sreg[PER];
    unsigned int todo = 0;
    #pragma unroll
    for (int k = 0; k < PER; ++k) {
        int c0 = (int)(short)(cpair[k] & 0xFFFFu);
        int c1 = (int)(short)(cpair[k] >> 16);
        int s = 0;
        if (c0 < 0) {
            int id = -c0 - 1;
            bool rr = (layout == 2) ? (reroll_raw[id] != 0)
                     : (layout == 1) ? (rf[id] != 0.0f)
                                     : (ri[id] != 0);
            s |= rr ? 2 : 1;
        }
        if (c1 < 0) {
            int id = -c1 - 1;
            bool rr = (layout == 2) ? (reroll_raw[id] != 0)
                     : (layout == 1) ? (rf[id] != 0.0f)
                                     : (ri[id] != 0);
            s |= rr ? 2 : 1;
        }
        if ((c0 < 0 && c1 < 0) || s == 3) s |= 4;
        else todo |= 1u << k;
        sreg[k] = s;
        state[b0 + k] = (unsigned char)s;
    }
    if (tid == 0) reach[0] = 1;
    __syncthreads();

    // ---- phase 1: SW1 fixed merged sweeps (R5 body), 1 barrier each ----
    unsigned int pushed = 0;
    #pragma unroll 1
    for (int s = 0; s < SW1; ++s) {
        uint4 rv = *(const uint4*)&reach[b0];
        unsigned int mm;
        mm  =  ((rv.x * 0x01020408u) >> 24) & 0xFu;
        mm |= (((rv.y * 0x01020408u) >> 24) & 0xFu) << 4;
        mm |= (((rv.z * 0x01020408u) >> 24) & 0xFu) << 8;
        mm |= (((rv.w * 0x01020408u) >> 24) & 0xFu) << 12;
        unsigned int newp = mm & ~pushed;
        if (newp) {
            pushed |= newp;
            #pragma unroll
            for (int k = 0; k < PER; ++k) {
                if ((newp >> k) & 1u) {
                    int c0 = (int)(short)(cpair[k] & 0xFFFFu);
                    int c1 = (int)(short)(cpair[k] >> 16);
                    if (c0 > 0) reach[c0] = (unsigned char)1;
                    if (c1 > 0) reach[c1] = (unsigned char)1;
                }
            }
        }
        if (todo) {
            int tl[PER], tr[PER];
            #pragma unroll
            for (int k = 0; k < PER; ++k) {
                bool act = (todo >> k) & 1u;
                int c0 = (int)(short)(cpair[k] & 0xFFFFu);
                int c1 = (int)(short)(cpair[k] >> 16);
                int la = (act && c0 > 0) ? c0 : NN;
                int ra = (act && c1 > 0) ? c1 : NN;
                tl[k] = state[la];
                tr[k] = state[ra];
            }
            #pragma unroll
            for (int k = 0; k < PER; ++k) {
                if ((todo >> k) & 1u) {
                    int sl = tl[k], sr = tr[k];
                    int ns = sreg[k] | (sl & 3) | (sr & 3);
                    bool fin = ((sl & sr & 4) != 0) || ((ns & 3) == 3);
                    if (fin) { ns |= 4; todo &= ~(1u << k); }
                    if (ns != sreg[k]) {
                        sreg[k] = ns;
                        state[b0 + k] = (unsigned char)ns;
                    }
                }
            }
        }
        __syncthreads();
    }

    // ---- compact unresolved backward nodes into worklist ----
    if (todo) {
        #pragma unroll
        for (int k = 0; k < PER; ++k) {
            if ((todo >> k) & 1u) {
                int idx = atomicAdd(&wl_n, 1);
                wl[idx] = (unsigned short)(b0 + k);
            }
        }
    }
    __syncthreads();

    // ---- phase 2: wave 0 finishes both fixpoints, barrier-free (lockstep) ----
    if (tid < 64) {
        const int l = tid;
        unsigned int pushedw[8];
        #pragma unroll
        for (int w8 = 0; w8 < 8; ++w8) {
            uint4 u0 = *(const uint4*)&reach[l * 256 + w8 * 32];
            uint4 u1 = *(const uint4*)&reach[l * 256 + w8 * 32 + 16];
            unsigned int m;
            m  =  ((u0.x * 0x01020408u) >> 24) & 0xFu;
            m |= (((u0.y * 0x01020408u) >> 24) & 0xFu) << 4;
            m |= (((u0.z * 0x01020408u) >> 24) & 0xFu) << 8;
            m |= (((u0.w * 0x01020408u) >> 24) & 0xFu) << 12;
            m |= (((u1.x * 0x01020408u) >> 24) & 0xFu) << 16;
            m |= (((u1.y * 0x01020408u) >> 24) & 0xFu) << 20;
            m |= (((u1.z * 0x01020408u) >> 24) & 0xFu) << 24;
            m |= (((u1.w * 0x01020408u) >> 24) & 0xFu) << 28;
            bits[l * 8 + w8] = m;
            pushedw[w8] = 0u;
        }
        const int n2 = wl_n;
        bool fdone = false;
        for (int it = 0; it < 300; ++it) {
            // forward: bit-packed poll + push-once
            bool any_new = false;
            if (!fdone) {
                #pragma unroll
                for (int w8 = 0; w8 < 8; ++w8) {
                    unsigned int cur = bits[l * 8 + w8];
                    unsigned int nw = cur & ~pushedw[w8];
                    pushedw[w8] = cur;
                    while (nw) {
                        int b = __builtin_ctz(nw);
                        nw &= nw - 1u;
                        int node = l * 256 + w8 * 32 + b;
                        unsigned int pr = pairs[node];
                        int c0 = (int)(short)(pr & 0xFFFFu);
                        int c1 = (int)(short)(pr >> 16);
                        if (c0 > 0) atomicOr(&bits[c0 >> 5], 1u << (c0 & 31));
                        if (c1 > 0) atomicOr(&bits[c1 >> 5], 1u << (c1 & 31));
                        any_new = true;
                    }
                }
                fdone = !__any(any_new);
            }
            // backward: worklist pass with sentinel kill
            bool blive = false;
            for (int i = l; i < n2; i += 64) {
                int n = wl[i];
                if (n != 0xFFFF) {
                    int st = state[n];
                    unsigned int pr = pairs[n];
                    int c0 = (int)(short)(pr & 0xFFFFu);
                    int c1 = (int)(short)(pr >> 16);
                    int s0 = (c0 > 0) ? (int)state[c0] : 4;
                    int s1 = (c1 > 0) ? (int)state[c1] : 4;
                    int ns = st | (s0 & 3) | (s1 & 3);
                    bool fin = ((s0 & s1 & 4) != 0) || ((ns & 3) == 3);
                    if (fin) {
                        state[n] = (unsigned char)(ns | 4);
                        wl[i] = 0xFFFF;
                    } else {
                        if (ns != st) state[n] = (unsigned char)ns;
                        blive = true;
                    }
                }
            }
            if (fdone && !__any(blive)) break;
            asm volatile("" ::: "memory");
        }
    }
    __syncthreads();

    // ---- count from bit array: popc + wave reduce, one atomic per wave ----
    unsigned int m16 = (bits[tid >> 1] >> ((tid & 1) * 16)) & 0xFFFFu;
    {
        int cc = __popc(m16);
        #pragma unroll
        for (int off = 32; off; off >>= 1) cc += __shfl_down(cc, off);
        if ((tid & 63) == 0) atomicAdd(&cnt, cc);
    }

    // ---- outputs: a from bits, h/r from state LDS, int4 stores ----
    int4* out4 = (int4*)out;
    #pragma unroll
    for (int j = 0; j < 4; ++j) {
        int4 a;
        a.x = (m16 >> (4*j+0)) & 1;
        a.y = (m16 >> (4*j+1)) & 1;
        a.z = (m16 >> (4*j+2)) & 1;
        a.w = (m16 >> (4*j+3)) & 1;
        out4[(b0 >> 2) + j] = a;
    }
    {
        uint4 sv = *(const uint4*)&state[b0];
        unsigned int wd[4] = {sv.x, sv.y, sv.z, sv.w};
        #pragma unroll
        for (int j = 0; j < 4; ++j) {
            int4 h, r;
            h.x = (wd[j] >> 0)  & 1; h.y = (wd[j] >> 8)  & 1;
            h.z = (wd[j] >> 16) & 1; h.w = (wd[j] >> 24) & 1;
            r.x = (wd[j] >> 1)  & 1; r.y = (wd[j] >> 9)  & 1;
            r.z = (wd[j] >> 17) & 1; r.w = (wd[j] >> 25) & 1;
            out4[((NN + b0) >> 2) + j]     = h;
            out4[((2 * NN + b0) >> 2) + j] = r;
        }
    }
    __syncthreads();
    if (tid == 0) out[3 * NN] = cnt;
}

extern "C" void kernel_launch(void* const* d_in, const int* in_sizes, int n_in,
                              void* d_out, int out_size, void* d_ws, size_t ws_size,
                              hipStream_t stream)
{
    const int* left  = (const int*)d_in[3];
    const int* right = (const int*)d_in[4];
    const unsigned char* reroll = (const unsigned char*)d_in[5];
    int* out = (int*)d_out;
    dag_eval_kernel<<<1, NT, 0, stream>>>(left, right, reroll, out);
}